// Round 1
// baseline (3996.650 us; speedup 1.0000x reference)
//
#include <hip/hip_runtime.h>
#include <math.h>

#define NB 8
#define NN 4096
#define NS 1024
#define NC 128
#define MID 64
#define CIN 131
#define COUT 256

// ---------------------------------------------------------------- FPS
// one block per batch, 512 threads; 8 points/thread in registers.
// Exact f32 semantics (no fma contraction) + first-index argmax tie-break
// to match the JAX reference's index decisions.
__global__ void fps_kernel(const float* __restrict__ xyz, int* __restrict__ fps_idx) {
#pragma clang fp contract(off)
  const int b = blockIdx.x;
  const int tid = threadIdx.x;
  const int lane = tid & 63, wv_id = tid >> 6;
  __shared__ float xs[NN], ys[NN], zs[NN];
  __shared__ float wv[8];
  __shared__ int wi[8];
  __shared__ int bshare;
  const float* base = xyz + (size_t)b * NN * 3;
  for (int t = tid; t < NN; t += 512) {
    xs[t] = base[3 * t]; ys[t] = base[3 * t + 1]; zs[t] = base[3 * t + 2];
  }
  __syncthreads();
  float px[8], py[8], pz[8], dd[8];
#pragma unroll
  for (int q = 0; q < 8; q++) {
    int j = q * 512 + tid;
    px[q] = xs[j]; py[q] = ys[j]; pz[q] = zs[j]; dd[q] = 1e10f;
  }
  float lx = xs[0], ly = ys[0], lz = zs[0];
  if (tid == 0) fps_idx[b * NS] = 0;
  for (int it = 1; it < NS; ++it) {
    float bv = -1.0f; int bi = 0x7fffffff;
#pragma unroll
    for (int q = 0; q < 8; q++) {
      float dx = px[q] - lx, dy = py[q] - ly, dz = pz[q] - lz;
      float d2 = dx * dx + dy * dy + dz * dz;
      float dn = fminf(dd[q], d2);
      dd[q] = dn;
      if (dn > bv) { bv = dn; bi = q * 512 + tid; }  // ascending j: keeps first on tie
    }
#pragma unroll
    for (int m = 1; m < 64; m <<= 1) {
      float ov = __shfl_xor(bv, m);
      int   oi = __shfl_xor(bi, m);
      if (ov > bv || (ov == bv && oi < bi)) { bv = ov; bi = oi; }
    }
    if (lane == 0) { wv[wv_id] = bv; wi[wv_id] = bi; }
    __syncthreads();
    if (tid == 0) {
      float fv = wv[0]; int fi = wi[0];
      for (int w = 1; w < 8; w++) {
        float ov = wv[w]; int oi = wi[w];
        if (ov > fv || (ov == fv && oi < fi)) { fv = ov; fi = oi; }
      }
      fps_idx[b * NS + it] = fi;
      bshare = fi;
    }
    __syncthreads();
    int li = bshare;
    lx = xs[li]; ly = ys[li]; lz = zs[li];
  }
}

// ---------------------------------------------------------------- new_xyz gather
__global__ void newxyz_kernel(const float* __restrict__ xyz, const int* __restrict__ fps,
                              float* __restrict__ out) {
  int t = blockIdx.x * blockDim.x + threadIdx.x;
  if (t >= NB * NS) return;
  int b = t >> 10;
  int j = fps[t];
  const float* p = xyz + ((size_t)b * NN + j) * 3;
  float* o = out + (size_t)t * 3;
  o[0] = p[0]; o[1] = p[1]; o[2] = p[2];
}

// ---------------------------------------------------------------- features (B,C,N)->(B,N,C)
__global__ void ft_kernel(const float* __restrict__ f, float* __restrict__ ft) {
  __shared__ float tile[32][33];
  int n0 = blockIdx.x * 32, c0 = blockIdx.y * 32, b = blockIdx.z;
  int tx = threadIdx.x, ty = threadIdx.y;  // 32x8
  for (int r = 0; r < 32; r += 8)
    tile[ty + r][tx] = f[((size_t)b * NC + (c0 + ty + r)) * NN + n0 + tx];
  __syncthreads();
  for (int r = 0; r < 32; r += 8)
    ft[((size_t)b * NN + n0 + ty + r) * NC + c0 + tx] = tile[tx][ty + r];
}

// ---------------------------------------------------------------- Wcr (256,131) -> (131,256)
__global__ void wcrt_kernel(const float* __restrict__ Wcr, float* __restrict__ wcrT) {
  int t = blockIdx.x * blockDim.x + threadIdx.x;
  if (t >= CIN * COUT) return;
  int c = t % COUT, d = t / COUT;
  wcrT[t] = Wcr[c * CIN + d];
}

// ---------------------------------------------------------------- ball query
// thread-per-center, xyz staged in LDS, ascending-index scan to first K hits.
template <int K>
__global__ void ball_kernel(const float* __restrict__ xyz, const float* __restrict__ nxyz,
                            int* __restrict__ idx, float r2) {
#pragma clang fp contract(off)
  __shared__ float xs[NN], ys[NN], zs[NN];
  const int b = blockIdx.x >> 2;
  const int s = ((blockIdx.x & 3) << 8) + threadIdx.x;
  const float* base = xyz + (size_t)b * NN * 3;
  for (int t = threadIdx.x; t < NN; t += 256) {
    xs[t] = base[3 * t]; ys[t] = base[3 * t + 1]; zs[t] = base[3 * t + 2];
  }
  __syncthreads();
  const int c = b * NS + s;
  const float cx = nxyz[c * 3], cy = nxyz[c * 3 + 1], cz = nxyz[c * 3 + 2];
  int cnt = 0, first = 0;
  int* o = idx + (size_t)c * K;
  for (int j = 0; j < NN; j++) {
    float dx = xs[j] - cx, dy = ys[j] - cy, dz = zs[j] - cz;
    float d2 = dx * dx + dy * dy + dz * dz;
    if (d2 < r2) {
      if (cnt == 0) first = j;
      o[cnt] = j;
      cnt++;
      if (cnt == K) break;
    }
  }
  for (int k = cnt; k < K; k++) o[k] = first;
}

// ---------------------------------------------------------------- grouped MLP phases
// lane = neighbor k (K=64: 1 center/wave; K=32: 2 centers/wave).
// PHASE 1: stats of y = h@W1^T + b1          (64 ch)
// PHASE 2: stats of p = (W2 t + b2) * x      (131 ch)
// PHASE 3: xm = max_k relu(bn2(p))           -> xm (B*S,131)
// bp layout: sc1@0 sh1@64 sc2@128 sh2@272 ; st layout: y@0/64, p@128/259
template <int K, int PHASE>
__global__ __launch_bounds__(256) void phase_kernel(
    const float* __restrict__ xyz, const float* __restrict__ nxyz,
    const float* __restrict__ feat, const float* __restrict__ ft,
    const int* __restrict__ idx,
    const float* __restrict__ W1, const float* __restrict__ b1,
    const float* __restrict__ W2, const float* __restrict__ b2,
    const float* __restrict__ bp, double* __restrict__ st,
    float* __restrict__ xm) {
  __shared__ float accS[CIN], accQ[CIN];
  const int tid = threadIdx.x, lane = tid & 63, wave = tid >> 6;
  if (PHASE <= 2) {
    for (int t = tid; t < CIN; t += 256) { accS[t] = 0.f; accQ[t] = 0.f; }
    __syncthreads();
  }
  const int G = 64 / K;
  const int sub = lane / K;
  const int k = lane % K;
  const int CPB = 4 * G;
  const int center = blockIdx.x * CPB + wave * G + sub;
  const int b = center / NS;
  const int* ip = idx + (size_t)center * K;
  const int j = ip[k];
  const int j0 = ip[0];
  const float* xb = xyz + (size_t)b * NN * 3;
  const float gxx = xb[3 * j], gxy = xb[3 * j + 1], gxz = xb[3 * j + 2];
  const float c0x = xb[3 * j0], c0y = xb[3 * j0 + 1], c0z = xb[3 * j0 + 2];
  const float cx = nxyz[center * 3], cy = nxyz[center * 3 + 1], cz = nxyz[center * 3 + 2];
  const float rx = gxx - cx, ry = gxy - cy, rz = gxz - cz;
  const float dst = sqrtf(rx * rx + ry * ry + rz * rz + 1e-12f);
  float h[10] = {dst, c0x, c0y, c0z, gxx, gxy, gxz, rx, ry, rz};
  float t[MID];
#pragma unroll
  for (int c = 0; c < MID; c++) {
    float a = b1[c];
    const float* w = W1 + c * 10;
#pragma unroll
    for (int d = 0; d < 10; d++) a += h[d] * w[d];
    t[c] = a;
  }
  if (PHASE == 1) {
#pragma unroll
    for (int c = 0; c < MID; c++) {
      float v = t[c], q = v * v;
#pragma unroll
      for (int m = 1; m < 64; m <<= 1) { v += __shfl_xor(v, m); q += __shfl_xor(q, m); }
      if (lane == 0) { atomicAdd(&accS[c], v); atomicAdd(&accQ[c], q); }
    }
    __syncthreads();
    if (tid < MID) {
      atomicAdd(&st[tid], (double)accS[tid]);
      atomicAdd(&st[64 + tid], (double)accQ[tid]);
    }
    return;
  }
#pragma unroll
  for (int c = 0; c < MID; c++) t[c] = fmaxf(bp[c] * t[c] + bp[64 + c], 0.0f);

  const float* ftb = ft ? (ft + ((size_t)b * NN + j) * NC) : nullptr;
  const float* fb = feat + (size_t)b * NC * NN + j;
  for (int c = 0; c < CIN; c++) {
    float z = b2[c];
    const float4* w4 = reinterpret_cast<const float4*>(W2 + c * MID);
#pragma unroll
    for (int d4 = 0; d4 < MID / 4; d4++) {
      float4 w = w4[d4];
      z += t[4 * d4 + 0] * w.x + t[4 * d4 + 1] * w.y + t[4 * d4 + 2] * w.z + t[4 * d4 + 3] * w.w;
    }
    float x;
    if (c == 0) x = rx;
    else if (c == 1) x = ry;
    else if (c == 2) x = rz;
    else x = ftb ? ftb[c - 3] : fb[(size_t)(c - 3) * NN];
    float p = z * x;
    if (PHASE == 2) {
      float v = p, q = p * p;
#pragma unroll
      for (int m = 1; m < 64; m <<= 1) { v += __shfl_xor(v, m); q += __shfl_xor(q, m); }
      if (lane == 0) { atomicAdd(&accS[c], v); atomicAdd(&accQ[c], q); }
    } else {
      float v = fmaxf(bp[128 + c] * p + bp[272 + c], 0.0f);
#pragma unroll
      for (int m = 1; m < K; m <<= 1) v = fmaxf(v, __shfl_xor(v, m));
      if (k == c % K) xm[(size_t)center * CIN + c] = v;
    }
  }
  if (PHASE == 2) {
    __syncthreads();
    if (tid < CIN) {
      atomicAdd(&st[128 + tid], (double)accS[tid]);
      atomicAdd(&st[259 + tid], (double)accQ[tid]);
    }
  }
}

// ---------------------------------------------------------------- BN finalize
__global__ void fin_kernel(const double* __restrict__ st, int soff, int qoff,
                           const float* __restrict__ g, const float* __restrict__ bt,
                           float* __restrict__ bp, int scoff, int shoff,
                           int nch, int cnt) {
  int c = threadIdx.x;
  if (c >= nch) return;
  double mean = st[soff + c] / (double)cnt;
  double var = st[qoff + c] / (double)cnt - mean * mean;
  if (var < 0.0) var = 0.0;
  float is = (float)(1.0 / sqrt(var + 1e-5));
  float sc = g[c] * is;
  float sh = bt[c] - (float)mean * sc;
  bp[scoff + c] = sc;
  bp[shoff + c] = sh;
}

// ---------------------------------------------------------------- 131->256 linear (+stats)
__global__ __launch_bounds__(256) void s4_kernel(const float* __restrict__ xm,
                                                 const float* __restrict__ wcrT,
                                                 const float* __restrict__ bcr,
                                                 float* __restrict__ y3t,
                                                 double* __restrict__ st) {
  __shared__ float xms[8][CIN];
  const int tid = threadIdx.x;
  float bc = bcr[tid];
  float s1 = 0.f, s2 = 0.f;
  for (int r0 = blockIdx.x * 8; r0 < NB * NS; r0 += gridDim.x * 8) {
    for (int t = tid; t < 8 * CIN; t += 256) {
      int rr = t / CIN, cc = t % CIN;
      xms[rr][cc] = xm[(size_t)(r0 + rr) * CIN + cc];
    }
    __syncthreads();
    float acc[8];
#pragma unroll
    for (int u = 0; u < 8; u++) acc[u] = bc;
    for (int d = 0; d < CIN; d++) {
      float w = wcrT[d * COUT + tid];
#pragma unroll
      for (int u = 0; u < 8; u++) acc[u] += xms[u][d] * w;
    }
#pragma unroll
    for (int u = 0; u < 8; u++) {
      int r = r0 + u;
      int b = r >> 10, s = r & (NS - 1);
      y3t[((size_t)b * COUT + tid) * NS + s] = acc[u];
      s1 += acc[u];
      s2 += acc[u] * acc[u];
    }
    __syncthreads();
  }
  atomicAdd(&st[512 + tid], (double)s1);
  atomicAdd(&st[768 + tid], (double)s2);
}

// ---------------------------------------------------------------- BN3 + relu + write out
__global__ void s5_kernel(const float* __restrict__ y3t, const float* __restrict__ bp,
                          float* __restrict__ outf, int choff) {
  int t = blockIdx.x * blockDim.x + threadIdx.x;
  int s = t & (NS - 1);
  int c = (t >> 10) & (COUT - 1);
  int b = t >> 18;
  float v = y3t[t];
  v = fmaxf(bp[512 + c] * v + bp[768 + c], 0.0f);
  outf[((size_t)b * 512 + choff + c) * NS + s] = v;
}

// ================================================================ host
extern "C" void kernel_launch(void* const* d_in, const int* in_sizes, int n_in,
                              void* d_out, int out_size, void* d_ws, size_t ws_size,
                              hipStream_t stream) {
  const float* xyz  = (const float*)d_in[0];
  const float* feat = (const float*)d_in[1];
  const float* W1   = (const float*)d_in[2];
  const float* b1   = (const float*)d_in[3];
  const float* W2   = (const float*)d_in[4];
  const float* b2   = (const float*)d_in[5];
  const float* Wcr  = (const float*)d_in[6];
  const float* bcr  = (const float*)d_in[7];
  const float* g_map = (const float*)d_in[8];
  const float* b_map = (const float*)d_in[9];
  const float* g_rs  = (const float*)d_in[10];
  const float* b_rs  = (const float*)d_in[11];
  const float* g_cr  = (const float*)d_in[12];
  const float* b_cr  = (const float*)d_in[13];

  char* wsb = (char*)d_ws;
  size_t off = 0;
  auto take = [&](size_t bytes) -> void* {
    void* p = wsb + off;
    off = (off + bytes + 255) & ~(size_t)255;
    return p;
  };
  int*    fps   = (int*)take((size_t)NB * NS * sizeof(int));
  int*    idxb  = (int*)take((size_t)NB * NS * 64 * sizeof(int));
  float*  xm    = (float*)take((size_t)NB * NS * CIN * sizeof(float));
  float*  y3t   = (float*)take((size_t)NB * NS * COUT * sizeof(float));
  float*  wcrT  = (float*)take((size_t)CIN * COUT * sizeof(float));
  double* stats = (double*)take(2048 * sizeof(double));
  float*  bnp   = (float*)take(2048 * sizeof(float));
  float*  ft    = nullptr;
  if (off + (size_t)NB * NN * NC * sizeof(float) <= ws_size)
    ft = (float*)take((size_t)NB * NN * NC * sizeof(float));

  float* out = (float*)d_out;
  float* feats = out + NB * NS * 3;

  hipMemsetAsync(stats, 0, 2048 * sizeof(double), stream);
  fps_kernel<<<NB, 512, 0, stream>>>(xyz, fps);
  newxyz_kernel<<<(NB * NS + 255) / 256, 256, 0, stream>>>(xyz, fps, out);
  if (ft) ft_kernel<<<dim3(NN / 32, NC / 32, NB), dim3(32, 8), 0, stream>>>(feat, ft);
  wcrt_kernel<<<(CIN * COUT + 255) / 256, 256, 0, stream>>>(Wcr, wcrT);

  const float r2s[2] = {(float)(0.1 * 0.1), (float)(0.2 * 0.2)};
  for (int i = 0; i < 2; i++) {
    double* st = stats + i * 1024;
    float* bp = bnp + i * 1024;
    const int K = (i == 0) ? 32 : 64;
    const int cnt = NB * NS * K;
    if (i == 0) {
      ball_kernel<32><<<32, 256, 0, stream>>>(xyz, out, idxb, r2s[0]);
      phase_kernel<32, 1><<<1024, 256, 0, stream>>>(xyz, out, feat, ft, idxb, W1, b1, W2, b2, bp, st, xm);
      fin_kernel<<<1, 256, 0, stream>>>(st, 0, 64, g_map, b_map, bp, 0, 64, MID, cnt);
      phase_kernel<32, 2><<<1024, 256, 0, stream>>>(xyz, out, feat, ft, idxb, W1, b1, W2, b2, bp, st, xm);
      fin_kernel<<<1, 256, 0, stream>>>(st, 128, 259, g_rs, b_rs, bp, 128, 272, CIN, cnt);
      phase_kernel<32, 3><<<1024, 256, 0, stream>>>(xyz, out, feat, ft, idxb, W1, b1, W2, b2, bp, st, xm);
    } else {
      ball_kernel<64><<<32, 256, 0, stream>>>(xyz, out, idxb, r2s[1]);
      phase_kernel<64, 1><<<2048, 256, 0, stream>>>(xyz, out, feat, ft, idxb, W1, b1, W2, b2, bp, st, xm);
      fin_kernel<<<1, 256, 0, stream>>>(st, 0, 64, g_map + 64, b_map + 64, bp, 0, 64, MID, cnt);
      phase_kernel<64, 2><<<2048, 256, 0, stream>>>(xyz, out, feat, ft, idxb, W1, b1, W2, b2, bp, st, xm);
      fin_kernel<<<1, 256, 0, stream>>>(st, 128, 259, g_rs + 131, b_rs + 131, bp, 128, 272, CIN, cnt);
      phase_kernel<64, 3><<<2048, 256, 0, stream>>>(xyz, out, feat, ft, idxb, W1, b1, W2, b2, bp, st, xm);
    }
    s4_kernel<<<64, 256, 0, stream>>>(xm, wcrT, bcr, y3t, st);
    fin_kernel<<<1, 256, 0, stream>>>(st, 512, 768, g_cr + i * 256, b_cr + i * 256, bp, 512, 768, COUT, NB * NS);
    s5_kernel<<<(NB * COUT * NS) / 256, 256, 0, stream>>>(y3t, bp, feats, i * 256);
  }
  (void)in_sizes; (void)n_in; (void)out_size;
}

// Round 2
// 2869.645 us; speedup vs baseline: 1.3927x; 1.3927x over previous
//
#include <hip/hip_runtime.h>
#include <math.h>

#define NB 8
#define NN 4096
#define NS 1024
#define NC 128
#define MID 64
#define CIN 131
#define COUT 256

// ---------------------------------------------------------------- FPS
// one block per batch, 512 threads, 8 pts/thread. One barrier per iteration:
// u64 packed key (dist_bits<<32 | (65535-idx)) -> wave shuffle-max ->
// leaders write wkey[parity][w] -> barrier -> all threads combine 8 keys.
// contract(off) + min-index tie-break to match reference index decisions.
__global__ void fps_kernel(const float* __restrict__ xyz, int* __restrict__ fps_idx) {
#pragma clang fp contract(off)
  const int b = blockIdx.x;
  const int tid = threadIdx.x;
  const int lane = tid & 63, w = tid >> 6;
  __shared__ float xs[NN], ys[NN], zs[NN];
  __shared__ unsigned long long wkey[2][8];
  const float* base = xyz + (size_t)b * NN * 3;
  for (int t = tid; t < NN; t += 512) {
    xs[t] = base[3 * t]; ys[t] = base[3 * t + 1]; zs[t] = base[3 * t + 2];
  }
  __syncthreads();
  float px[8], py[8], pz[8], dd[8];
#pragma unroll
  for (int q = 0; q < 8; q++) {
    int j = q * 512 + tid;
    px[q] = xs[j]; py[q] = ys[j]; pz[q] = zs[j]; dd[q] = 1e10f;
  }
  float lx = xs[0], ly = ys[0], lz = zs[0];
  if (tid == 0) fps_idx[b * NS] = 0;
  for (int it = 1; it < NS; ++it) {
    float bv = -1.0f; int bi = 0;
#pragma unroll
    for (int q = 0; q < 8; q++) {
      float dx = px[q] - lx, dy = py[q] - ly, dz = pz[q] - lz;
      float d2 = dx * dx + dy * dy + dz * dz;
      float dn = fminf(dd[q], d2);
      dd[q] = dn;
      if (dn > bv) { bv = dn; bi = q * 512 + tid; }  // ascending j keeps first on tie
    }
    unsigned long long key =
        ((unsigned long long)__float_as_uint(bv) << 32) | (unsigned)(65535 - bi);
#pragma unroll
    for (int m = 1; m < 64; m <<= 1) {
      unsigned lo = (unsigned)key, hi = (unsigned)(key >> 32);
      unsigned olo = __shfl_xor(lo, m), ohi = __shfl_xor(hi, m);
      unsigned long long o = ((unsigned long long)ohi << 32) | olo;
      if (o > key) key = o;
    }
    const int p = it & 1;
    if (lane == 0) wkey[p][w] = key;
    __syncthreads();
    unsigned long long kk = wkey[p][0];
#pragma unroll
    for (int u = 1; u < 8; u++) {
      unsigned long long o = wkey[p][u];
      if (o > kk) kk = o;
    }
    int li = 65535 - (int)(kk & 0xFFFFu);
    if (tid == 0) fps_idx[b * NS + it] = li;
    lx = xs[li]; ly = ys[li]; lz = zs[li];
  }
}

// ---------------------------------------------------------------- new_xyz gather
__global__ void newxyz_kernel(const float* __restrict__ xyz, const int* __restrict__ fps,
                              float* __restrict__ out) {
  int t = blockIdx.x * blockDim.x + threadIdx.x;
  if (t >= NB * NS) return;
  int b = t >> 10;
  int j = fps[t];
  const float* p = xyz + ((size_t)b * NN + j) * 3;
  float* o = out + (size_t)t * 3;
  o[0] = p[0]; o[1] = p[1]; o[2] = p[2];
}

// ---------------------------------------------------------------- features (B,C,N)->(B,N,C)
__global__ void ft_kernel(const float* __restrict__ f, float* __restrict__ ft) {
  __shared__ float tile[32][33];
  int n0 = blockIdx.x * 32, c0 = blockIdx.y * 32, b = blockIdx.z;
  int tx = threadIdx.x, ty = threadIdx.y;  // 32x8
  for (int r = 0; r < 32; r += 8)
    tile[ty + r][tx] = f[((size_t)b * NC + (c0 + ty + r)) * NN + n0 + tx];
  __syncthreads();
  for (int r = 0; r < 32; r += 8)
    ft[((size_t)b * NN + n0 + ty + r) * NC + c0 + tx] = tile[tx][ty + r];
}

// ---------------------------------------------------------------- Wcr (256,131) -> (131,256)
__global__ void wcrt_kernel(const float* __restrict__ Wcr, float* __restrict__ wcrT) {
  int t = blockIdx.x * blockDim.x + threadIdx.x;
  if (t >= CIN * COUT) return;
  int c = t % COUT, d = t / COUT;
  wcrT[t] = Wcr[c * CIN + d];
}

// ---------------------------------------------------------------- ball query
// 128 blocks x 64 threads (one wave, 64 centers/block), xyz staged in LDS.
template <int K>
__global__ void ball_kernel(const float* __restrict__ xyz, const float* __restrict__ nxyz,
                            int* __restrict__ idx, float r2) {
#pragma clang fp contract(off)
  __shared__ float xs[NN], ys[NN], zs[NN];
  const int b = blockIdx.x >> 4;
  const int s = ((blockIdx.x & 15) << 6) + threadIdx.x;
  const float* base = xyz + (size_t)b * NN * 3;
  for (int t = threadIdx.x; t < NN; t += 64) {
    xs[t] = base[3 * t]; ys[t] = base[3 * t + 1]; zs[t] = base[3 * t + 2];
  }
  __syncthreads();
  const int c = b * NS + s;
  const float cx = nxyz[c * 3], cy = nxyz[c * 3 + 1], cz = nxyz[c * 3 + 2];
  int cnt = 0, first = 0;
  int* o = idx + (size_t)c * K;
  for (int j = 0; j < NN; j++) {
    float dx = xs[j] - cx, dy = ys[j] - cy, dz = zs[j] - cz;
    float d2 = dx * dx + dy * dy + dz * dz;
    if (d2 < r2) {
      if (cnt == 0) first = j;
      o[cnt] = j;
      cnt++;
      if (cnt == K) break;
    }
  }
  for (int k = cnt; k < K; k++) o[k] = first;
}

// ---------------------------------------------------------------- P1: stats of y = h@W1^T+b1
template <int K>
__global__ __launch_bounds__(256) void p1_kernel(
    const float* __restrict__ xyz, const float* __restrict__ nxyz,
    const int* __restrict__ idx,
    const float* __restrict__ W1, const float* __restrict__ b1,
    double* __restrict__ st) {
  __shared__ float accS[MID], accQ[MID];
  const int tid = threadIdx.x, lane = tid & 63, wave = tid >> 6;
  if (tid < MID) { accS[tid] = 0.f; accQ[tid] = 0.f; }
  __syncthreads();
  const int G = 64 / K;
  const int sub = lane / K;
  const int k = lane % K;
  const int center = blockIdx.x * (4 * G) + wave * G + sub;
  const int b = center / NS;
  const int* ip = idx + (size_t)center * K;
  const int j = ip[k];
  const int j0 = ip[0];
  const float* xb = xyz + (size_t)b * NN * 3;
  const float gxx = xb[3 * j], gxy = xb[3 * j + 1], gxz = xb[3 * j + 2];
  const float c0x = xb[3 * j0], c0y = xb[3 * j0 + 1], c0z = xb[3 * j0 + 2];
  const float cx = nxyz[center * 3], cy = nxyz[center * 3 + 1], cz = nxyz[center * 3 + 2];
  const float rx = gxx - cx, ry = gxy - cy, rz = gxz - cz;
  const float dst = sqrtf(rx * rx + ry * ry + rz * rz + 1e-12f);
  float h[10] = {dst, c0x, c0y, c0z, gxx, gxy, gxz, rx, ry, rz};
#pragma unroll
  for (int c = 0; c < MID; c++) {
    float a = b1[c];
    const float* wp = W1 + c * 10;
#pragma unroll
    for (int d = 0; d < 10; d++) a += h[d] * wp[d];
    float v = a, q = a * a;
#pragma unroll
    for (int m = 1; m < 64; m <<= 1) { v += __shfl_xor(v, m); q += __shfl_xor(q, m); }
    if (lane == 0) { atomicAdd(&accS[c], v); atomicAdd(&accQ[c], q); }
  }
  __syncthreads();
  if (tid < MID) {
    atomicAdd(&st[tid], (double)accS[tid]);
    atomicAdd(&st[64 + tid], (double)accQ[tid]);
  }
}

// ---------------------------------------------------------------- P2: stats of p AND max_k p
// bn1 params computed in-block from st. pm[center][c] = max_k p (pre-BN2).
template <int K>
__global__ __launch_bounds__(256) void p2_kernel(
    const float* __restrict__ xyz, const float* __restrict__ nxyz,
    const float* __restrict__ feat, const float* __restrict__ ft,
    const int* __restrict__ idx,
    const float* __restrict__ W1, const float* __restrict__ b1,
    const float* __restrict__ W2, const float* __restrict__ b2,
    const float* __restrict__ g1, const float* __restrict__ bt1,
    double* __restrict__ st, float* __restrict__ pm) {
  __shared__ float accS[CIN], accQ[CIN];
  __shared__ float sc1[MID], sh1[MID];
  const int tid = threadIdx.x, lane = tid & 63, wave = tid >> 6;
  for (int t = tid; t < CIN; t += 256) { accS[t] = 0.f; accQ[t] = 0.f; }
  if (tid < MID) {
    const double cnt = (double)NB * NS * K;
    double mean = st[tid] / cnt;
    double var = st[64 + tid] / cnt - mean * mean;
    if (var < 0.0) var = 0.0;
    float is = (float)(1.0 / sqrt(var + 1e-5));
    float sc = g1[tid] * is;
    sc1[tid] = sc;
    sh1[tid] = bt1[tid] - (float)mean * sc;
  }
  __syncthreads();
  const int G = 64 / K;
  const int sub = lane / K;
  const int k = lane % K;
  const int center = blockIdx.x * (4 * G) + wave * G + sub;
  const int b = center / NS;
  const int* ip = idx + (size_t)center * K;
  const int j = ip[k];
  const int j0 = ip[0];
  const float* xb = xyz + (size_t)b * NN * 3;
  const float gxx = xb[3 * j], gxy = xb[3 * j + 1], gxz = xb[3 * j + 2];
  const float c0x = xb[3 * j0], c0y = xb[3 * j0 + 1], c0z = xb[3 * j0 + 2];
  const float cx = nxyz[center * 3], cy = nxyz[center * 3 + 1], cz = nxyz[center * 3 + 2];
  const float rx = gxx - cx, ry = gxy - cy, rz = gxz - cz;
  const float dst = sqrtf(rx * rx + ry * ry + rz * rz + 1e-12f);
  float h[10] = {dst, c0x, c0y, c0z, gxx, gxy, gxz, rx, ry, rz};
  float t[MID];
#pragma unroll
  for (int c = 0; c < MID; c++) {
    float a = b1[c];
    const float* wp = W1 + c * 10;
#pragma unroll
    for (int d = 0; d < 10; d++) a += h[d] * wp[d];
    t[c] = fmaxf(sc1[c] * a + sh1[c], 0.0f);
  }
  const float* ftb = ft ? (ft + ((size_t)b * NN + j) * NC) : nullptr;
  const float* fb = feat + (size_t)b * NC * NN + j;
  for (int c = 0; c < CIN; c++) {
    float z = b2[c];
    const float4* w4 = reinterpret_cast<const float4*>(W2 + c * MID);
#pragma unroll
    for (int d4 = 0; d4 < MID / 4; d4++) {
      float4 w = w4[d4];
      z += t[4 * d4 + 0] * w.x + t[4 * d4 + 1] * w.y + t[4 * d4 + 2] * w.z + t[4 * d4 + 3] * w.w;
    }
    float x;
    if (c == 0) x = rx;
    else if (c == 1) x = ry;
    else if (c == 2) x = rz;
    else x = ftb ? ftb[c - 3] : fb[(size_t)(c - 3) * NN];
    float p = z * x;
    float v = p, q = p * p;
#pragma unroll
    for (int m = 1; m < 64; m <<= 1) { v += __shfl_xor(v, m); q += __shfl_xor(q, m); }
    if (lane == 0) { atomicAdd(&accS[c], v); atomicAdd(&accQ[c], q); }
    float pmax = p;
#pragma unroll
    for (int m = 1; m < K; m <<= 1) pmax = fmaxf(pmax, __shfl_xor(pmax, m));
    if (k == (c & (K - 1))) pm[(size_t)center * CIN + c] = pmax;
  }
  __syncthreads();
  if (tid < CIN) {
    atomicAdd(&st[128 + tid], (double)accS[tid]);
    atomicAdd(&st[259 + tid], (double)accQ[tid]);
  }
}

// ---------------------------------------------------------------- 131->256 linear (+stats)
// applies bn2+relu (params from st) to pm during tile load.
__global__ __launch_bounds__(256) void s4_kernel(const float* __restrict__ pm,
                                                 const float* __restrict__ wcrT,
                                                 const float* __restrict__ bcr,
                                                 const float* __restrict__ g2,
                                                 const float* __restrict__ bt2,
                                                 float* __restrict__ y3t,
                                                 double* __restrict__ st, int K) {
  __shared__ float xms[8][CIN];
  __shared__ float sc2[CIN], sh2[CIN];
  const int tid = threadIdx.x;
  if (tid < CIN) {
    const double cnt = (double)NB * NS * K;
    double mean = st[128 + tid] / cnt;
    double var = st[259 + tid] / cnt - mean * mean;
    if (var < 0.0) var = 0.0;
    float is = (float)(1.0 / sqrt(var + 1e-5));
    float sc = g2[tid] * is;
    sc2[tid] = sc;
    sh2[tid] = bt2[tid] - (float)mean * sc;
  }
  float bc = bcr[tid];
  float s1 = 0.f, s2 = 0.f;
  __syncthreads();
  for (int r0 = blockIdx.x * 8; r0 < NB * NS; r0 += gridDim.x * 8) {
    for (int t = tid; t < 8 * CIN; t += 256) {
      int rr = t / CIN, cc = t % CIN;
      xms[rr][cc] = fmaxf(sc2[cc] * pm[(size_t)(r0 + rr) * CIN + cc] + sh2[cc], 0.0f);
    }
    __syncthreads();
    float acc[8];
#pragma unroll
    for (int u = 0; u < 8; u++) acc[u] = bc;
    for (int d = 0; d < CIN; d++) {
      float w = wcrT[d * COUT + tid];
#pragma unroll
      for (int u = 0; u < 8; u++) acc[u] += xms[u][d] * w;
    }
#pragma unroll
    for (int u = 0; u < 8; u++) {
      int r = r0 + u;
      int b = r >> 10, s = r & (NS - 1);
      y3t[((size_t)b * COUT + tid) * NS + s] = acc[u];
      s1 += acc[u];
      s2 += acc[u] * acc[u];
    }
    __syncthreads();
  }
  atomicAdd(&st[512 + tid], (double)s1);
  atomicAdd(&st[768 + tid], (double)s2);
}

// ---------------------------------------------------------------- BN3 + relu + write out
__global__ void s5_kernel(const float* __restrict__ y3t, const double* __restrict__ st,
                          const float* __restrict__ g3, const float* __restrict__ bt3,
                          float* __restrict__ outf, int choff) {
  int t = blockIdx.x * blockDim.x + threadIdx.x;
  int s = t & (NS - 1);
  int c = (t >> 10) & (COUT - 1);
  int b = t >> 18;
  double mean = st[512 + c] / (double)(NB * NS);
  double var = st[768 + c] / (double)(NB * NS) - mean * mean;
  if (var < 0.0) var = 0.0;
  float is = (float)(1.0 / sqrt(var + 1e-5));
  float sc = g3[c] * is;
  float sh = bt3[c] - (float)mean * sc;
  float v = y3t[t];
  outf[((size_t)b * 512 + choff + c) * NS + s] = fmaxf(sc * v + sh, 0.0f);
}

// ================================================================ host
extern "C" void kernel_launch(void* const* d_in, const int* in_sizes, int n_in,
                              void* d_out, int out_size, void* d_ws, size_t ws_size,
                              hipStream_t stream) {
  const float* xyz  = (const float*)d_in[0];
  const float* feat = (const float*)d_in[1];
  const float* W1   = (const float*)d_in[2];
  const float* b1   = (const float*)d_in[3];
  const float* W2   = (const float*)d_in[4];
  const float* b2   = (const float*)d_in[5];
  const float* Wcr  = (const float*)d_in[6];
  const float* bcr  = (const float*)d_in[7];
  const float* g_map = (const float*)d_in[8];
  const float* b_map = (const float*)d_in[9];
  const float* g_rs  = (const float*)d_in[10];
  const float* b_rs  = (const float*)d_in[11];
  const float* g_cr  = (const float*)d_in[12];
  const float* b_cr  = (const float*)d_in[13];

  char* wsb = (char*)d_ws;
  size_t off = 0;
  auto take = [&](size_t bytes) -> void* {
    void* p = wsb + off;
    off = (off + bytes + 255) & ~(size_t)255;
    return p;
  };
  int*    fps   = (int*)take((size_t)NB * NS * sizeof(int));
  int*    idxb  = (int*)take((size_t)NB * NS * 64 * sizeof(int));
  float*  xm    = (float*)take((size_t)NB * NS * CIN * sizeof(float));
  float*  y3t   = (float*)take((size_t)NB * NS * COUT * sizeof(float));
  float*  wcrT  = (float*)take((size_t)CIN * COUT * sizeof(float));
  double* stats = (double*)take(2048 * sizeof(double));
  float*  ft    = nullptr;
  if (off + (size_t)NB * NN * NC * sizeof(float) <= ws_size)
    ft = (float*)take((size_t)NB * NN * NC * sizeof(float));

  float* out = (float*)d_out;
  float* feats = out + NB * NS * 3;

  hipMemsetAsync(stats, 0, 2048 * sizeof(double), stream);
  fps_kernel<<<NB, 512, 0, stream>>>(xyz, fps);
  newxyz_kernel<<<(NB * NS + 255) / 256, 256, 0, stream>>>(xyz, fps, out);
  if (ft) ft_kernel<<<dim3(NN / 32, NC / 32, NB), dim3(32, 8), 0, stream>>>(feat, ft);
  wcrt_kernel<<<(CIN * COUT + 255) / 256, 256, 0, stream>>>(Wcr, wcrT);

  const float r2s[2] = {(float)(0.1 * 0.1), (float)(0.2 * 0.2)};
  for (int i = 0; i < 2; i++) {
    double* st = stats + i * 1024;
    if (i == 0) {
      ball_kernel<32><<<128, 64, 0, stream>>>(xyz, out, idxb, r2s[0]);
      p1_kernel<32><<<1024, 256, 0, stream>>>(xyz, out, idxb, W1, b1, st);
      p2_kernel<32><<<1024, 256, 0, stream>>>(xyz, out, feat, ft, idxb, W1, b1, W2, b2,
                                              g_map, b_map, st, xm);
    } else {
      ball_kernel<64><<<128, 64, 0, stream>>>(xyz, out, idxb, r2s[1]);
      p1_kernel<64><<<2048, 256, 0, stream>>>(xyz, out, idxb, W1, b1, st);
      p2_kernel<64><<<2048, 256, 0, stream>>>(xyz, out, feat, ft, idxb, W1, b1, W2, b2,
                                              g_map + 64, b_map + 64, st, xm);
    }
    const int K = (i == 0) ? 32 : 64;
    s4_kernel<<<64, 256, 0, stream>>>(xm, wcrT, bcr, g_rs + i * CIN, b_rs + i * CIN,
                                      y3t, st, K);
    s5_kernel<<<(NB * COUT * NS) / 256, 256, 0, stream>>>(y3t, st, g_cr + i * 256,
                                                          b_cr + i * 256, feats, i * 256);
  }
  (void)in_sizes; (void)n_in; (void)out_size;
}

// Round 3
// 2725.412 us; speedup vs baseline: 1.4664x; 1.0529x over previous
//
#include <hip/hip_runtime.h>
#include <math.h>

#define NB 8
#define NN 4096
#define NS 1024
#define NC 128
#define MID 64
#define CIN 131
#define COUT 256

// ---------------------------------------------------------------- FPS
// (unchanged from round 2 — 816us; candidate for round-3 work)
__global__ void fps_kernel(const float* __restrict__ xyz, int* __restrict__ fps_idx) {
#pragma clang fp contract(off)
  const int b = blockIdx.x;
  const int tid = threadIdx.x;
  const int lane = tid & 63, w = tid >> 6;
  __shared__ float xs[NN], ys[NN], zs[NN];
  __shared__ unsigned long long wkey[2][8];
  const float* base = xyz + (size_t)b * NN * 3;
  for (int t = tid; t < NN; t += 512) {
    xs[t] = base[3 * t]; ys[t] = base[3 * t + 1]; zs[t] = base[3 * t + 2];
  }
  __syncthreads();
  float px[8], py[8], pz[8], dd[8];
#pragma unroll
  for (int q = 0; q < 8; q++) {
    int j = q * 512 + tid;
    px[q] = xs[j]; py[q] = ys[j]; pz[q] = zs[j]; dd[q] = 1e10f;
  }
  float lx = xs[0], ly = ys[0], lz = zs[0];
  if (tid == 0) fps_idx[b * NS] = 0;
  for (int it = 1; it < NS; ++it) {
    float bv = -1.0f; int bi = 0;
#pragma unroll
    for (int q = 0; q < 8; q++) {
      float dx = px[q] - lx, dy = py[q] - ly, dz = pz[q] - lz;
      float d2 = dx * dx + dy * dy + dz * dz;
      float dn = fminf(dd[q], d2);
      dd[q] = dn;
      if (dn > bv) { bv = dn; bi = q * 512 + tid; }
    }
    unsigned long long key =
        ((unsigned long long)__float_as_uint(bv) << 32) | (unsigned)(65535 - bi);
#pragma unroll
    for (int m = 1; m < 64; m <<= 1) {
      unsigned lo = (unsigned)key, hi = (unsigned)(key >> 32);
      unsigned olo = __shfl_xor(lo, m), ohi = __shfl_xor(hi, m);
      unsigned long long o = ((unsigned long long)ohi << 32) | olo;
      if (o > key) key = o;
    }
    const int p = it & 1;
    if (lane == 0) wkey[p][w] = key;
    __syncthreads();
    unsigned long long kk = wkey[p][0];
#pragma unroll
    for (int u = 1; u < 8; u++) {
      unsigned long long o = wkey[p][u];
      if (o > kk) kk = o;
    }
    int li = 65535 - (int)(kk & 0xFFFFu);
    if (tid == 0) fps_idx[b * NS + it] = li;
    lx = xs[li]; ly = ys[li]; lz = zs[li];
  }
}

// ---------------------------------------------------------------- new_xyz gather
__global__ void newxyz_kernel(const float* __restrict__ xyz, const int* __restrict__ fps,
                              float* __restrict__ out) {
  int t = blockIdx.x * blockDim.x + threadIdx.x;
  if (t >= NB * NS) return;
  int b = t >> 10;
  int j = fps[t];
  const float* p = xyz + ((size_t)b * NN + j) * 3;
  float* o = out + (size_t)t * 3;
  o[0] = p[0]; o[1] = p[1]; o[2] = p[2];
}

// ---------------------------------------------------------------- features (B,C,N)->(B,N,C)
__global__ void ft_kernel(const float* __restrict__ f, float* __restrict__ ft) {
  __shared__ float tile[32][33];
  int n0 = blockIdx.x * 32, c0 = blockIdx.y * 32, b = blockIdx.z;
  int tx = threadIdx.x, ty = threadIdx.y;  // 32x8
  for (int r = 0; r < 32; r += 8)
    tile[ty + r][tx] = f[((size_t)b * NC + (c0 + ty + r)) * NN + n0 + tx];
  __syncthreads();
  for (int r = 0; r < 32; r += 8)
    ft[((size_t)b * NN + n0 + ty + r) * NC + c0 + tx] = tile[tx][ty + r];
}

// ---------------------------------------------------------------- Wcr (256,131) -> (131,256)
__global__ void wcrt_kernel(const float* __restrict__ Wcr, float* __restrict__ wcrT) {
  int t = blockIdx.x * blockDim.x + threadIdx.x;
  if (t >= CIN * COUT) return;
  int c = t % COUT, d = t / COUT;
  wcrT[t] = Wcr[c * CIN + d];
}

// ---------------------------------------------------------------- ball query
template <int K>
__global__ void ball_kernel(const float* __restrict__ xyz, const float* __restrict__ nxyz,
                            int* __restrict__ idx, float r2) {
#pragma clang fp contract(off)
  __shared__ float xs[NN], ys[NN], zs[NN];
  const int b = blockIdx.x >> 4;
  const int s = ((blockIdx.x & 15) << 6) + threadIdx.x;
  const float* base = xyz + (size_t)b * NN * 3;
  for (int t = threadIdx.x; t < NN; t += 64) {
    xs[t] = base[3 * t]; ys[t] = base[3 * t + 1]; zs[t] = base[3 * t + 2];
  }
  __syncthreads();
  const int c = b * NS + s;
  const float cx = nxyz[c * 3], cy = nxyz[c * 3 + 1], cz = nxyz[c * 3 + 2];
  int cnt = 0, first = 0;
  int* o = idx + (size_t)c * K;
  for (int j = 0; j < NN; j++) {
    float dx = xs[j] - cx, dy = ys[j] - cy, dz = zs[j] - cz;
    float d2 = dx * dx + dy * dy + dz * dz;
    if (d2 < r2) {
      if (cnt == 0) first = j;
      o[cnt] = j;
      cnt++;
      if (cnt == K) break;
    }
  }
  for (int k = cnt; k < K; k++) o[k] = first;
}

// ---------------------------------------------------------------- P1: stats of y = h@W1^T+b1
template <int K>
__global__ __launch_bounds__(256) void p1_kernel(
    const float* __restrict__ xyz, const float* __restrict__ nxyz,
    const int* __restrict__ idx,
    const float* __restrict__ W1, const float* __restrict__ b1,
    double* __restrict__ st) {
  __shared__ float accS[MID], accQ[MID];
  const int tid = threadIdx.x, lane = tid & 63, wave = tid >> 6;
  if (tid < MID) { accS[tid] = 0.f; accQ[tid] = 0.f; }
  __syncthreads();
  const int G = 64 / K;
  const int sub = lane / K;
  const int k = lane % K;
  const int center = blockIdx.x * (4 * G) + wave * G + sub;
  const int b = center / NS;
  const int* ip = idx + (size_t)center * K;
  const int j = ip[k];
  const int j0 = ip[0];
  const float* xb = xyz + (size_t)b * NN * 3;
  const float gxx = xb[3 * j], gxy = xb[3 * j + 1], gxz = xb[3 * j + 2];
  const float c0x = xb[3 * j0], c0y = xb[3 * j0 + 1], c0z = xb[3 * j0 + 2];
  const float cx = nxyz[center * 3], cy = nxyz[center * 3 + 1], cz = nxyz[center * 3 + 2];
  const float rx = gxx - cx, ry = gxy - cy, rz = gxz - cz;
  const float dst = sqrtf(rx * rx + ry * ry + rz * rz + 1e-12f);
  float h[10] = {dst, c0x, c0y, c0z, gxx, gxy, gxz, rx, ry, rz};
#pragma unroll
  for (int c = 0; c < MID; c++) {
    float a = b1[c];
    const float* wp = W1 + c * 10;
#pragma unroll
    for (int d = 0; d < 10; d++) a += h[d] * wp[d];
    float v = a, q = a * a;
#pragma unroll
    for (int m = 1; m < 64; m <<= 1) { v += __shfl_xor(v, m); q += __shfl_xor(q, m); }
    if (lane == 0) { atomicAdd(&accS[c], v); atomicAdd(&accQ[c], q); }
  }
  __syncthreads();
  if (tid < MID) {
    atomicAdd(&st[tid], (double)accS[tid]);
    atomicAdd(&st[64 + tid], (double)accQ[tid]);
  }
}

// ---------------------------------------------------------------- P2: stats of p AND max_k p
// XCD-swizzled blocks (batch == blockIdx%8); per-lane sequential float4
// feature reads; bn1 params computed in-block; pm = max_k p (pre-BN2).
template <int K, bool UFT>
__global__ __launch_bounds__(256) void p2_kernel(
    const float* __restrict__ xyz, const float* __restrict__ nxyz,
    const float* __restrict__ feat, const float* __restrict__ ft,
    const int* __restrict__ idx,
    const float* __restrict__ W1, const float* __restrict__ b1,
    const float* __restrict__ W2, const float* __restrict__ b2,
    const float* __restrict__ g1, const float* __restrict__ bt1,
    double* __restrict__ st, float* __restrict__ pm) {
  __shared__ float accS[CIN], accQ[CIN];
  __shared__ float sc1[MID], sh1[MID];
  const int tid = threadIdx.x, lane = tid & 63, wave = tid >> 6;
  for (int t = tid; t < CIN; t += 256) { accS[t] = 0.f; accQ[t] = 0.f; }
  if (tid < MID) {
    const double cnt = (double)NB * NS * K;
    double mean = st[tid] / cnt;
    double var = st[64 + tid] / cnt - mean * mean;
    if (var < 0.0) var = 0.0;
    float is = (float)(1.0 / sqrt(var + 1e-5));
    float sc = g1[tid] * is;
    sc1[tid] = sc;
    sh1[tid] = bt1[tid] - (float)mean * sc;
  }
  __syncthreads();
  // XCD swizzle: logical block lb chosen so batch == blockIdx%8 == XCD id
  const int per = gridDim.x >> 3;
  const int lb = (blockIdx.x & 7) * per + (blockIdx.x >> 3);
  const int G = 64 / K;
  const int sub = lane / K;
  const int k = lane % K;
  const int center = lb * (4 * G) + wave * G + sub;
  const int b = center / NS;
  const int* ip = idx + (size_t)center * K;
  const int j = ip[k];
  const int j0 = ip[0];
  const float* xb = xyz + (size_t)b * NN * 3;
  const float gxx = xb[3 * j], gxy = xb[3 * j + 1], gxz = xb[3 * j + 2];
  const float c0x = xb[3 * j0], c0y = xb[3 * j0 + 1], c0z = xb[3 * j0 + 2];
  const float cx = nxyz[center * 3], cy = nxyz[center * 3 + 1], cz = nxyz[center * 3 + 2];
  const float rx = gxx - cx, ry = gxy - cy, rz = gxz - cz;
  const float dst = sqrtf(rx * rx + ry * ry + rz * rz + 1e-12f);
  float h[10] = {dst, c0x, c0y, c0z, gxx, gxy, gxz, rx, ry, rz};
  float t[MID];
#pragma unroll
  for (int c = 0; c < MID; c++) {
    float a = b1[c];
    const float* wp = W1 + c * 10;
#pragma unroll
    for (int d = 0; d < 10; d++) a += h[d] * wp[d];
    t[c] = fmaxf(sc1[c] * a + sh1[c], 0.0f);
  }
  auto chan = [&](int c, float x) {
    float z = b2[c];
    const float4* w4 = reinterpret_cast<const float4*>(W2 + c * MID);
#pragma unroll
    for (int d4 = 0; d4 < MID / 4; d4++) {
      float4 w = w4[d4];
      z += t[4 * d4 + 0] * w.x + t[4 * d4 + 1] * w.y + t[4 * d4 + 2] * w.z + t[4 * d4 + 3] * w.w;
    }
    float p = z * x;
    float v = p, q = p * p;
#pragma unroll
    for (int m = 1; m < 64; m <<= 1) { v += __shfl_xor(v, m); q += __shfl_xor(q, m); }
    if (lane == 0) { atomicAdd(&accS[c], v); atomicAdd(&accQ[c], q); }
    float pmax = p;
#pragma unroll
    for (int m = 1; m < K; m <<= 1) pmax = fmaxf(pmax, __shfl_xor(pmax, m));
    if (k == (c & (K - 1))) pm[(size_t)center * CIN + c] = pmax;
  };
  chan(0, rx); chan(1, ry); chan(2, rz);
  const float4* ftb4 = UFT ? reinterpret_cast<const float4*>(ft + ((size_t)b * NN + j) * NC)
                           : nullptr;
  const float* fb = feat + (size_t)b * NC * NN + j;
  for (int f0 = 0; f0 < NC; f0 += 4) {
    float4 fr;
    if (UFT) {
      fr = ftb4[f0 >> 2];
    } else {
      fr.x = fb[(size_t)f0 * NN]; fr.y = fb[(size_t)(f0 + 1) * NN];
      fr.z = fb[(size_t)(f0 + 2) * NN]; fr.w = fb[(size_t)(f0 + 3) * NN];
    }
    chan(3 + f0, fr.x); chan(4 + f0, fr.y); chan(5 + f0, fr.z); chan(6 + f0, fr.w);
  }
  __syncthreads();
  if (tid < CIN) {
    atomicAdd(&st[128 + tid], (double)accS[tid]);
    atomicAdd(&st[259 + tid], (double)accQ[tid]);
  }
}

// ---------------------------------------------------------------- 131->256 linear (+stats)
// bn2+relu applied to pm during tile load; writes RAW linear output directly
// into d_out feats region (s5 normalizes in place).
__global__ __launch_bounds__(256) void s4_kernel(const float* __restrict__ pm,
                                                 const float* __restrict__ wcrT,
                                                 const float* __restrict__ bcr,
                                                 const float* __restrict__ g2,
                                                 const float* __restrict__ bt2,
                                                 float* __restrict__ feats, int choff,
                                                 double* __restrict__ st, int K) {
  __shared__ float xms[8][CIN];
  __shared__ float sc2[CIN], sh2[CIN];
  const int tid = threadIdx.x;
  if (tid < CIN) {
    const double cnt = (double)NB * NS * K;
    double mean = st[128 + tid] / cnt;
    double var = st[259 + tid] / cnt - mean * mean;
    if (var < 0.0) var = 0.0;
    float is = (float)(1.0 / sqrt(var + 1e-5));
    float sc = g2[tid] * is;
    sc2[tid] = sc;
    sh2[tid] = bt2[tid] - (float)mean * sc;
  }
  float bc = bcr[tid];
  float s1 = 0.f, s2 = 0.f;
  __syncthreads();
  for (int r0 = blockIdx.x * 8; r0 < NB * NS; r0 += gridDim.x * 8) {
    for (int t = tid; t < 8 * CIN; t += 256) {
      int rr = t / CIN, cc = t % CIN;
      xms[rr][cc] = fmaxf(sc2[cc] * pm[(size_t)(r0 + rr) * CIN + cc] + sh2[cc], 0.0f);
    }
    __syncthreads();
    float acc[8];
#pragma unroll
    for (int u = 0; u < 8; u++) acc[u] = bc;
    for (int d = 0; d < CIN; d++) {
      float w = wcrT[d * COUT + tid];
#pragma unroll
      for (int u = 0; u < 8; u++) acc[u] += xms[u][d] * w;
    }
#pragma unroll
    for (int u = 0; u < 8; u++) {
      int r = r0 + u;
      int b = r >> 10, s = r & (NS - 1);
      feats[((size_t)b * 512 + choff + tid) * NS + s] = acc[u];
      s1 += acc[u];
      s2 += acc[u] * acc[u];
    }
    __syncthreads();
  }
  atomicAdd(&st[512 + tid], (double)s1);
  atomicAdd(&st[768 + tid], (double)s2);
}

// ---------------------------------------------------------------- BN3 + relu in place
__global__ void s5_kernel(float* __restrict__ feats, const double* __restrict__ st,
                          const float* __restrict__ g3, const float* __restrict__ bt3,
                          int choff) {
  int t = blockIdx.x * blockDim.x + threadIdx.x;
  int s = t & (NS - 1);
  int c = (t >> 10) & (COUT - 1);
  int b = t >> 18;
  double mean = st[512 + c] / (double)(NB * NS);
  double var = st[768 + c] / (double)(NB * NS) - mean * mean;
  if (var < 0.0) var = 0.0;
  float is = (float)(1.0 / sqrt(var + 1e-5));
  float sc = g3[c] * is;
  float sh = bt3[c] - (float)mean * sc;
  size_t o = ((size_t)b * 512 + choff + c) * NS + s;
  feats[o] = fmaxf(sc * feats[o] + sh, 0.0f);
}

// ================================================================ host
extern "C" void kernel_launch(void* const* d_in, const int* in_sizes, int n_in,
                              void* d_out, int out_size, void* d_ws, size_t ws_size,
                              hipStream_t stream) {
  const float* xyz  = (const float*)d_in[0];
  const float* feat = (const float*)d_in[1];
  const float* W1   = (const float*)d_in[2];
  const float* b1   = (const float*)d_in[3];
  const float* W2   = (const float*)d_in[4];
  const float* b2   = (const float*)d_in[5];
  const float* Wcr  = (const float*)d_in[6];
  const float* bcr  = (const float*)d_in[7];
  const float* g_map = (const float*)d_in[8];
  const float* b_map = (const float*)d_in[9];
  const float* g_rs  = (const float*)d_in[10];
  const float* b_rs  = (const float*)d_in[11];
  const float* g_cr  = (const float*)d_in[12];
  const float* b_cr  = (const float*)d_in[13];

  char* wsb = (char*)d_ws;
  size_t off = 0;
  auto take = [&](size_t bytes) -> void* {
    void* p = wsb + off;
    off = (off + bytes + 255) & ~(size_t)255;
    return p;
  };
  int*    fps   = (int*)take((size_t)NB * NS * sizeof(int));
  int*    idxb  = (int*)take((size_t)NB * NS * 64 * sizeof(int));
  float*  xm    = (float*)take((size_t)NB * NS * CIN * sizeof(float));
  float*  wcrT  = (float*)take((size_t)CIN * COUT * sizeof(float));
  double* stats = (double*)take(2048 * sizeof(double));
  float*  ft    = nullptr;
  if (off + (size_t)NB * NN * NC * sizeof(float) + 256 <= ws_size)
    ft = (float*)take((size_t)NB * NN * NC * sizeof(float));

  float* out = (float*)d_out;
  float* feats = out + NB * NS * 3;

  hipMemsetAsync(stats, 0, 2048 * sizeof(double), stream);
  fps_kernel<<<NB, 512, 0, stream>>>(xyz, fps);
  newxyz_kernel<<<(NB * NS + 255) / 256, 256, 0, stream>>>(xyz, fps, out);
  if (ft) ft_kernel<<<dim3(NN / 32, NC / 32, NB), dim3(32, 8), 0, stream>>>(feat, ft);
  wcrt_kernel<<<(CIN * COUT + 255) / 256, 256, 0, stream>>>(Wcr, wcrT);

  const float r2s[2] = {(float)(0.1 * 0.1), (float)(0.2 * 0.2)};
  for (int i = 0; i < 2; i++) {
    double* st = stats + i * 1024;
    if (i == 0) {
      ball_kernel<32><<<128, 64, 0, stream>>>(xyz, out, idxb, r2s[0]);
      p1_kernel<32><<<1024, 256, 0, stream>>>(xyz, out, idxb, W1, b1, st);
      if (ft)
        p2_kernel<32, true><<<1024, 256, 0, stream>>>(xyz, out, feat, ft, idxb, W1, b1,
                                                      W2, b2, g_map, b_map, st, xm);
      else
        p2_kernel<32, false><<<1024, 256, 0, stream>>>(xyz, out, feat, ft, idxb, W1, b1,
                                                       W2, b2, g_map, b_map, st, xm);
    } else {
      ball_kernel<64><<<128, 64, 0, stream>>>(xyz, out, idxb, r2s[1]);
      p1_kernel<64><<<2048, 256, 0, stream>>>(xyz, out, idxb, W1, b1, st);
      if (ft)
        p2_kernel<64, true><<<2048, 256, 0, stream>>>(xyz, out, feat, ft, idxb, W1, b1,
                                                      W2, b2, g_map + 64, b_map + 64, st, xm);
      else
        p2_kernel<64, false><<<2048, 256, 0, stream>>>(xyz, out, feat, ft, idxb, W1, b1,
                                                       W2, b2, g_map + 64, b_map + 64, st, xm);
    }
    const int K = (i == 0) ? 32 : 64;
    s4_kernel<<<256, 256, 0, stream>>>(xm, wcrT, bcr, g_rs + i * CIN, b_rs + i * CIN,
                                       feats, i * 256, stats + i * 1024, K);
    s5_kernel<<<(NB * COUT * NS) / 256, 256, 0, stream>>>(feats, stats + i * 1024,
                                                          g_cr + i * 256, b_cr + i * 256,
                                                          i * 256);
  }
  (void)in_sizes; (void)n_in; (void)out_size;
}